// Round 1
// baseline (2043.027 us; speedup 1.0000x reference)
//
#include <hip/hip_runtime.h>
#include <math.h>

// Problem constants (B=4, S=2048, D=1024, H=16, d_k=64)
#define B_  4
#define S_  2048
#define D_  1024
#define H_  16
#define DK_ 64

// ---------------------------------------------------------------------------
// GEMM: C[M][N] = A[M][K] @ W[N][K]^T   (einsum 'md,nd->mn')
// 64x64 tile, BK=16, 256 threads, 4x4 register micro-tile per thread.
// ---------------------------------------------------------------------------
constexpr int BM = 64, BN = 64, BK = 16;

__global__ __launch_bounds__(256)
void gemm_xwt(const float* __restrict__ A, const float* __restrict__ W,
              float* __restrict__ C, int M, int N, int K)
{
    __shared__ float As[BK][BM + 4];   // [k][m], +4 pad keeps float4 alignment
    __shared__ float Ws[BK][BN + 4];   // [k][n]

    const int tid = threadIdx.x;
    const int tx  = tid & 15;          // n direction (4 cols each)
    const int ty  = tid >> 4;          // m direction (4 rows each)
    const int m0  = blockIdx.y * BM;
    const int n0  = blockIdx.x * BN;

    // loader: each thread brings one float4 of A and one of W per k-step
    const int lrow = tid >> 2;         // 0..63
    const int lk   = (tid & 3) * 4;    // 0,4,8,12
    const float* Ap = A + (size_t)(m0 + lrow) * K + lk;
    const float* Wp = W + (size_t)(n0 + lrow) * K + lk;

    float acc[4][4] = {};

    float4 av = *(const float4*)(Ap);
    float4 wv = *(const float4*)(Wp);

    for (int k0 = 0; k0 < K; k0 += BK) {
        __syncthreads();               // previous iteration done reading LDS
        As[lk + 0][lrow] = av.x; As[lk + 1][lrow] = av.y;
        As[lk + 2][lrow] = av.z; As[lk + 3][lrow] = av.w;
        Ws[lk + 0][lrow] = wv.x; Ws[lk + 1][lrow] = wv.y;
        Ws[lk + 2][lrow] = wv.z; Ws[lk + 3][lrow] = wv.w;
        // prefetch next k-step while this one computes
        if (k0 + BK < K) {
            av = *(const float4*)(Ap + k0 + BK);
            wv = *(const float4*)(Wp + k0 + BK);
        }
        __syncthreads();

        #pragma unroll
        for (int kk = 0; kk < BK; ++kk) {
            const float4 a4 = *(const float4*)&As[kk][ty * 4];
            const float4 w4 = *(const float4*)&Ws[kk][tx * 4];
            const float ai[4] = {a4.x, a4.y, a4.z, a4.w};
            const float wj[4] = {w4.x, w4.y, w4.z, w4.w};
            #pragma unroll
            for (int i = 0; i < 4; ++i)
                #pragma unroll
                for (int j = 0; j < 4; ++j)
                    acc[i][j] = fmaf(ai[i], wj[j], acc[i][j]);
        }
    }

    #pragma unroll
    for (int i = 0; i < 4; ++i) {
        float* Cp = C + (size_t)(m0 + ty * 4 + i) * N + n0 + tx * 4;
        *(float4*)Cp = make_float4(acc[i][0], acc[i][1], acc[i][2], acc[i][3]);
    }
}

// ---------------------------------------------------------------------------
// RoPE (in-place on q and k, layout [B,S,D] with D = H*DK interleaved heads)
// Accurate sincosf/powf: total trig count is tiny (~µs), matches f32 ref.
// ---------------------------------------------------------------------------
__global__ __launch_bounds__(256)
void rope_qk(float* q, float* k)
{
    const size_t row = blockIdx.x;          // b*S + s
    const int s  = (int)(row % S_);         // position
    const int t  = threadIdx.x;             // float4 index within the row
    const int dh = (t * 4) & (DK_ - 1);     // d within head (even)
    const int i0 = dh >> 1;                 // pair index for (x,y); (z,w)=i0+1

    const float p  = (float)s;
    const float f0 = powf(10000.0f, -(float)(2 * i0)       * (1.0f / 64.0f));
    const float f1 = powf(10000.0f, -(float)(2 * (i0 + 1)) * (1.0f / 64.0f));
    float s0, c0, s1, c1;
    sincosf(p * f0, &s0, &c0);
    sincosf(p * f1, &s1, &c1);

    float* qp = q + row * D_ + t * 4;
    float4 v = *(float4*)qp;
    float4 r;
    r.x = v.x * c0 - v.y * s0;
    r.y = v.x * s0 + v.y * c0;
    r.z = v.z * c1 - v.w * s1;
    r.w = v.z * s1 + v.w * c1;
    *(float4*)qp = r;

    float* kp = k + row * D_ + t * 4;
    float4 w = *(float4*)kp;
    float4 u;
    u.x = w.x * c0 - w.y * s0;
    u.y = w.x * s0 + w.y * c0;
    u.z = w.z * c1 - w.w * s1;
    u.w = w.z * s1 + w.w * c1;
    *(float4*)kp = u;
}

// ---------------------------------------------------------------------------
// Flash attention (fp32, causal). One block = one (b, h, 64-row q tile).
// LDS: Qs (scaled Q^T), SB (shared: K^T tile, then V tile), Ps (probs).
// Online softmax with per-row (m,l) carried in registers; rows live on
// 16-lane groups (shfl_xor reductions).
// NOTE: O may alias Q (each block writes exactly the region only it reads).
// ---------------------------------------------------------------------------
__global__ __launch_bounds__(256)
void flash_attn(const float* Q, const float* __restrict__ Kg,
                const float* __restrict__ Vg, float* O)
{
    __shared__ float Qs[DK_][64 + 4];  // [d][r], pre-scaled by 1/8
    __shared__ float SB[64][64 + 4];   // as K: [d][c]; as V: [c][d]
    __shared__ float Ps[64][64 + 4];   // [r][c]

    const int tid = threadIdx.x;
    const int tx  = tid & 15;          // col group (4 cols)
    const int ty  = tid >> 4;          // row group (4 rows)
    const int qt  = blockIdx.x;
    const int h   = blockIdx.y;
    const int b   = blockIdx.z;
    const int q0  = qt * 64;
    const int r   = tid >> 2;          // staging row 0..63
    const int fb  = tid & 3;           // staging float4 base

    // ---- stage Q tile (transposed, scaled) ----
    {
        const float* qp = Q + (size_t)(b * S_ + q0 + r) * D_ + h * DK_;
        #pragma unroll
        for (int u = 0; u < 4; ++u) {
            const int f = fb + 4 * u;
            const float4 qv = *(const float4*)(qp + f * 4);
            Qs[f * 4 + 0][r] = qv.x * 0.125f;
            Qs[f * 4 + 1][r] = qv.y * 0.125f;
            Qs[f * 4 + 2][r] = qv.z * 0.125f;
            Qs[f * 4 + 3][r] = qv.w * 0.125f;
        }
    }

    float m[4], l[4], o[4][4];
    #pragma unroll
    for (int i = 0; i < 4; ++i) {
        m[i] = -1e30f; l[i] = 0.0f;
        #pragma unroll
        for (int j = 0; j < 4; ++j) o[i][j] = 0.0f;
    }

    for (int kt = 0; kt <= qt; ++kt) {
        const int k0 = kt * 64;
        const float* kp = Kg + (size_t)(b * S_ + k0 + r) * D_ + h * DK_;
        const float* vp = Vg + (size_t)(b * S_ + k0 + r) * D_ + h * DK_;
        float4 kv[4], vv[4];
        #pragma unroll
        for (int u = 0; u < 4; ++u) {
            const int f = fb + 4 * u;
            kv[u] = *(const float4*)(kp + f * 4);
            vv[u] = *(const float4*)(vp + f * 4);
        }

        __syncthreads();               // prior PV done with SB(V) and Ps
        #pragma unroll
        for (int u = 0; u < 4; ++u) {  // K tile, transposed [d][c]
            const int f = fb + 4 * u;
            SB[f * 4 + 0][r] = kv[u].x;
            SB[f * 4 + 1][r] = kv[u].y;
            SB[f * 4 + 2][r] = kv[u].z;
            SB[f * 4 + 3][r] = kv[u].w;
        }
        __syncthreads();

        // ---- scores: S = (Q/8) @ K^T ----
        float sc[4][4] = {};
        #pragma unroll
        for (int kk = 0; kk < DK_; ++kk) {
            const float4 a4 = *(const float4*)&Qs[kk][ty * 4];
            const float4 b4 = *(const float4*)&SB[kk][tx * 4];
            const float ai[4] = {a4.x, a4.y, a4.z, a4.w};
            const float bj[4] = {b4.x, b4.y, b4.z, b4.w};
            #pragma unroll
            for (int i = 0; i < 4; ++i)
                #pragma unroll
                for (int j = 0; j < 4; ++j)
                    sc[i][j] = fmaf(ai[i], bj[j], sc[i][j]);
        }

        // causal mask only on the diagonal tile (k0 == q0)
        if (kt == qt) {
            #pragma unroll
            for (int i = 0; i < 4; ++i)
                #pragma unroll
                for (int j = 0; j < 4; ++j)
                    if (tx * 4 + j > ty * 4 + i) sc[i][j] = -1e30f;
        }

        // ---- online softmax (row = 16-lane group) ----
        #pragma unroll
        for (int i = 0; i < 4; ++i) {
            float rm = fmaxf(fmaxf(sc[i][0], sc[i][1]), fmaxf(sc[i][2], sc[i][3]));
            #pragma unroll
            for (int off = 1; off < 16; off <<= 1)
                rm = fmaxf(rm, __shfl_xor(rm, off));
            const float mn   = fmaxf(m[i], rm);
            const float corr = __expf(m[i] - mn);
            float rs = 0.0f;
            #pragma unroll
            for (int j = 0; j < 4; ++j) {
                sc[i][j] = __expf(sc[i][j] - mn);
                rs += sc[i][j];
            }
            #pragma unroll
            for (int off = 1; off < 16; off <<= 1)
                rs += __shfl_xor(rs, off);
            l[i] = l[i] * corr + rs;
            m[i] = mn;
            #pragma unroll
            for (int j = 0; j < 4; ++j) o[i][j] *= corr;
        }

        __syncthreads();               // everyone done reading SB as K
        #pragma unroll
        for (int u = 0; u < 4; ++u) {  // V tile, row-major [c][d]
            const int f = fb + 4 * u;
            *(float4*)&SB[r][f * 4] = vv[u];
        }
        #pragma unroll
        for (int i = 0; i < 4; ++i)
            *(float4*)&Ps[ty * 4 + i][tx * 4] =
                make_float4(sc[i][0], sc[i][1], sc[i][2], sc[i][3]);
        __syncthreads();

        // ---- O += P @ V ----
        #pragma unroll
        for (int k4 = 0; k4 < 16; ++k4) {
            float4 pv[4], ve[4];
            #pragma unroll
            for (int i = 0; i < 4; ++i)
                pv[i] = *(const float4*)&Ps[ty * 4 + i][k4 * 4];
            #pragma unroll
            for (int e = 0; e < 4; ++e)
                ve[e] = *(const float4*)&SB[k4 * 4 + e][tx * 4];
            #pragma unroll
            for (int i = 0; i < 4; ++i) {
                const float pi[4] = {pv[i].x, pv[i].y, pv[i].z, pv[i].w};
                #pragma unroll
                for (int e = 0; e < 4; ++e) {
                    o[i][0] = fmaf(pi[e], ve[e].x, o[i][0]);
                    o[i][1] = fmaf(pi[e], ve[e].y, o[i][1]);
                    o[i][2] = fmaf(pi[e], ve[e].z, o[i][2]);
                    o[i][3] = fmaf(pi[e], ve[e].w, o[i][3]);
                }
            }
        }
    }

    // ---- epilogue: O /= l, write [B,S,D] ----
    #pragma unroll
    for (int i = 0; i < 4; ++i) {
        const float inv = 1.0f / l[i];
        float* op = O + (size_t)(b * S_ + q0 + ty * 4 + i) * D_ + h * DK_ + tx * 4;
        *(float4*)op = make_float4(o[i][0] * inv, o[i][1] * inv,
                                   o[i][2] * inv, o[i][3] * inv);
    }
}

// ---------------------------------------------------------------------------
// Launch
// ---------------------------------------------------------------------------
extern "C" void kernel_launch(void* const* d_in, const int* in_sizes, int n_in,
                              void* d_out, int out_size, void* d_ws, size_t ws_size,
                              hipStream_t stream)
{
    const float* x   = (const float*)d_in[0];
    const float* w_q = (const float*)d_in[1];
    const float* w_k = (const float*)d_in[2];
    const float* w_v = (const float*)d_in[3];
    const float* w_o = (const float*)d_in[4];
    float* out = (float*)d_out;

    // workspace: q | k | v  (each B*S*D f32 = 33.55 MB; total 100.7 MB)
    const size_t TEN = (size_t)B_ * S_ * D_;
    float* q_ws = (float*)d_ws;
    float* k_ws = q_ws + TEN;
    float* v_ws = k_ws + TEN;
    // attention output aliases q_ws: block (b,h,qt) writes exactly the
    // [b, q0..q0+63, h*64..h*64+63] region that only it reads (race-free).
    float* a_ws = q_ws;

    const int M = B_ * S_;             // 8192
    dim3 gemmGrid(D_ / BN, M / BM);    // (16, 128)

    gemm_xwt<<<gemmGrid, 256, 0, stream>>>(x, w_q, q_ws, M, D_, D_);
    gemm_xwt<<<gemmGrid, 256, 0, stream>>>(x, w_k, k_ws, M, D_, D_);
    gemm_xwt<<<gemmGrid, 256, 0, stream>>>(x, w_v, v_ws, M, D_, D_);

    rope_qk<<<dim3(M), 256, 0, stream>>>(q_ws, k_ws);

    flash_attn<<<dim3(S_ / 64, H_, B_), 256, 0, stream>>>(q_ws, k_ws, v_ws, a_ws);

    gemm_xwt<<<gemmGrid, 256, 0, stream>>>(a_ws, w_o, out, M, D_, D_);
}

// Round 2
// 935.724 us; speedup vs baseline: 2.1834x; 2.1834x over previous
//
#include <hip/hip_runtime.h>
#include <math.h>

// Problem constants (B=4, S=2048, D=1024, H=16, d_k=64)
#define B_  4
#define S_  2048
#define D_  1024
#define H_  16
#define DK_ 64

typedef unsigned short u16;
typedef unsigned int   u32;
typedef short     shortx8 __attribute__((ext_vector_type(8)));
typedef float     floatx4 __attribute__((ext_vector_type(4)));
typedef u16       u16x4   __attribute__((ext_vector_type(4)));

// ---- bf16 helpers (RNE) ----
__device__ __forceinline__ u16 f2bf(float f) {
    u32 u = __float_as_uint(f);
    u += 0x7FFFu + ((u >> 16) & 1u);
    return (u16)(u >> 16);
}
__device__ __forceinline__ float bf2f(u16 b) {
    return __uint_as_float(((u32)b) << 16);
}

// ---- async global->LDS 16B ----
typedef const __attribute__((address_space(1))) u32* gp1_t;
typedef __attribute__((address_space(3))) u32* lp3_t;
__device__ __forceinline__ void async16(const void* g, void* l) {
    __builtin_amdgcn_global_load_lds((gp1_t)g, (lp3_t)l, 16, 0, 0);
}

#define MFMA(a, b, c) __builtin_amdgcn_mfma_f32_16x16x32_bf16((a), (b), (c), 0, 0, 0)

// ---------------------------------------------------------------------------
// split fp32 -> (hi, lo) bf16 planes
// ---------------------------------------------------------------------------
__global__ __launch_bounds__(256)
void split_bf16(const float* __restrict__ src, u16* __restrict__ dh,
                u16* __restrict__ dl, int n)
{
    int i = (blockIdx.x * 256 + threadIdx.x) * 4;
    if (i >= n) return;
    float4 v = *(const float4*)(src + i);
    u16 h0 = f2bf(v.x), h1 = f2bf(v.y), h2 = f2bf(v.z), h3 = f2bf(v.w);
    u16x4 hv = {h0, h1, h2, h3};
    u16x4 lv = {f2bf(v.x - bf2f(h0)), f2bf(v.y - bf2f(h1)),
                f2bf(v.z - bf2f(h2)), f2bf(v.w - bf2f(h3))};
    *(u16x4*)(dh + i) = hv;
    *(u16x4*)(dl + i) = lv;
}

// ---------------------------------------------------------------------------
// bf16x3 GEMM: C[M][N] = (Ah+Al)[M][K] @ (Wh+Wl)[N][K]^T  (3 MFMA passes)
// 128x128 tile, BK=32, 256 threads = 4 waves (2x2), 64x64 per wave.
// Staging via global_load_lds (16B). LDS [128][32] bf16, 64B rows -> uniform
// bank-group spread for ds_read_b128 (no pad needed).
// EPI: 0 = fp32 out, 1 = bf16-hi out (v), 2 = RoPE + hi/lo out (q,k)
// ---------------------------------------------------------------------------
template<int EPI>
__global__ __launch_bounds__(256)
void gemm_b3(const u16* __restrict__ Ah, const u16* __restrict__ Al,
             const u16* __restrict__ Wh, const u16* __restrict__ Wl,
             float* __restrict__ outF, u16* __restrict__ outH,
             u16* __restrict__ outL, int M, int N, int K, float scale)
{
    __shared__ __align__(16) u16 As[2][128][32];
    __shared__ __align__(16) u16 Ws[2][128][32];

    const int tid  = threadIdx.x;
    const int w    = tid >> 6;
    const int lane = tid & 63;
    const int lr   = lane & 15, lg = lane >> 4;
    const int wm   = w >> 1, wn = w & 1;
    const int m0   = blockIdx.x * 128, n0 = blockIdx.y * 128;

    // staging: wave w covers rows [w*32, w*32+32) of each operand plane.
    const int srow = w * 32 + (lane >> 2);
    const int sck  = (lane & 3) * 8;
    const u16* gAh = Ah + (size_t)(m0 + srow) * K + sck;
    const u16* gAl = Al + (size_t)(m0 + srow) * K + sck;
    const u16* gWh = Wh + (size_t)(n0 + srow) * K + sck;
    const u16* gWl = Wl + (size_t)(n0 + srow) * K + sck;
    const size_t r16 = (size_t)16 * K;

    u16* dAh = &As[0][w * 32][0];
    u16* dAl = &As[1][w * 32][0];
    u16* dWh = &Ws[0][w * 32][0];
    u16* dWl = &Ws[1][w * 32][0];

    floatx4 zero = {0.f, 0.f, 0.f, 0.f};
    floatx4 acc[4][4];
    #pragma unroll
    for (int i = 0; i < 4; ++i)
        #pragma unroll
        for (int j = 0; j < 4; ++j) acc[i][j] = zero;

    for (int kt = 0; kt < K; kt += 32) {
        __syncthreads();                       // prev reads done
        async16(gAh + kt,       dAh);
        async16(gAh + kt + r16, dAh + 512);
        async16(gAl + kt,       dAl);
        async16(gAl + kt + r16, dAl + 512);
        async16(gWh + kt,       dWh);
        async16(gWh + kt + r16, dWh + 512);
        async16(gWl + kt,       dWl);
        async16(gWl + kt + r16, dWl + 512);
        __syncthreads();                       // vmcnt(0) drained before barrier

        shortx8 a[4][2], bw[4][2];
        #pragma unroll
        for (int mi = 0; mi < 4; ++mi) {
            a[mi][0] = *(const shortx8*)&As[0][wm * 64 + mi * 16 + lr][lg * 8];
            a[mi][1] = *(const shortx8*)&As[1][wm * 64 + mi * 16 + lr][lg * 8];
        }
        #pragma unroll
        for (int ni = 0; ni < 4; ++ni) {
            bw[ni][0] = *(const shortx8*)&Ws[0][wn * 64 + ni * 16 + lr][lg * 8];
            bw[ni][1] = *(const shortx8*)&Ws[1][wn * 64 + ni * 16 + lr][lg * 8];
        }
        #pragma unroll
        for (int mi = 0; mi < 4; ++mi)
            #pragma unroll
            for (int ni = 0; ni < 4; ++ni) {
                acc[mi][ni] = MFMA(a[mi][0], bw[ni][0], acc[mi][ni]);
                acc[mi][ni] = MFMA(a[mi][0], bw[ni][1], acc[mi][ni]);
                acc[mi][ni] = MFMA(a[mi][1], bw[ni][0], acc[mi][ni]);
            }
    }

    // ---- epilogue ----  C value (mi,ni,r): row=m0+wm*64+mi*16+lg*4+r,
    //                                        col=n0+wn*64+ni*16+lr
    if constexpr (EPI == 0) {                  // fp32 write
        #pragma unroll
        for (int mi = 0; mi < 4; ++mi)
            #pragma unroll
            for (int ni = 0; ni < 4; ++ni)
                #pragma unroll
                for (int r = 0; r < 4; ++r) {
                    size_t row = m0 + wm * 64 + mi * 16 + lg * 4 + r;
                    size_t col = n0 + wn * 64 + ni * 16 + lr;
                    outF[row * N + col] = acc[mi][ni][r];
                }
    }
    if constexpr (EPI == 1) {                  // bf16 hi plane only (v)
        #pragma unroll
        for (int mi = 0; mi < 4; ++mi)
            #pragma unroll
            for (int ni = 0; ni < 4; ++ni)
                #pragma unroll
                for (int r = 0; r < 4; ++r) {
                    float v = acc[mi][ni][r];
                    u16 hv = f2bf(v);
                    u32 ph = (u32)__shfl_xor((int)hv, 1) & 0xFFFFu;
                    if (!(lr & 1)) {
                        size_t row = m0 + wm * 64 + mi * 16 + lg * 4 + r;
                        size_t col = n0 + wn * 64 + ni * 16 + lr;
                        *(u32*)(outH + row * N + col) = (u32)hv | (ph << 16);
                    }
                }
    }
    if constexpr (EPI == 2) {                  // RoPE + scale + hi/lo planes
        #pragma unroll
        for (int ni = 0; ni < 4; ++ni) {
            int din  = ni * 16 + lr;           // d within head (col mod 64)
            float fr = powf(10000.0f, -(float)(din >> 1) * (1.0f / 32.0f));
            #pragma unroll
            for (int mi = 0; mi < 4; ++mi)
                #pragma unroll
                for (int r = 0; r < 4; ++r) {
                    int row = m0 + wm * 64 + mi * 16 + lg * 4 + r;
                    float v  = acc[mi][ni][r];
                    float pv = __shfl_xor(v, 1);
                    float sa, ca;
                    sincosf((float)(row & (S_ - 1)) * fr, &sa, &ca);
                    float o = (v * ca + ((lr & 1) ? pv * sa : -pv * sa)) * scale;
                    u16 hv = f2bf(o);
                    u16 lv = f2bf(o - bf2f(hv));
                    u32 ph  = (u32)__shfl_xor((int)hv, 1) & 0xFFFFu;
                    u32 pl2 = (u32)__shfl_xor((int)lv, 1) & 0xFFFFu;
                    if (!(lr & 1)) {
                        size_t off = (size_t)row * N + n0 + wn * 64 + ni * 16 + lr;
                        *(u32*)(outH + off) = (u32)hv | (ph << 16);
                        *(u32*)(outL + off) = (u32)lv | (pl2 << 16);
                    }
                }
        }
    }
}

// ---------------------------------------------------------------------------
// Flash attention, bf16 MFMA. Block = (qt: 128 q-rows, h, b); 256 thr, 4 waves,
// each wave owns 32 q-rows (2 m-frags). K-loop over 64-key tiles (causal).
// QK^T = bf16x3 (q,k hi/lo); softmax fp32 (Q pre-scaled by 1/8); PV bf16.
// K LDS [64][72] (conflict-free b128), V transposed [d][key] [64][72],
// per-wave-private P tile (no barrier between P write and PV read).
// O written as hi/lo planes (may alias Q planes: block-disjoint regions).
// ---------------------------------------------------------------------------
__global__ __launch_bounds__(256)
void attn_mfma(const u16* __restrict__ Qh, const u16* __restrict__ Ql,
               const u16* __restrict__ Kh, const u16* __restrict__ Kl,
               const u16* __restrict__ Vh,
               u16* __restrict__ Oh, u16* __restrict__ Ol)
{
    __shared__ __align__(16) u16 Ks[2][64][72];
    __shared__ __align__(16) u16 Vt[64][72];
    __shared__ __align__(16) u16 Ps[4][32][72];

    const int tid  = threadIdx.x, w = tid >> 6, lane = tid & 63;
    const int lr   = lane & 15, lg = lane >> 4;
    const int qt   = blockIdx.x, h = blockIdx.y, b = blockIdx.z;
    const int q0   = qt * 128;
    const size_t rowbase = (size_t)b * S_;

    // Q fragments straight from global: qf[mf][ks][plane]
    shortx8 qf[2][2][2];
    #pragma unroll
    for (int mf = 0; mf < 2; ++mf) {
        size_t off = (rowbase + q0 + w * 32 + mf * 16 + lr) * D_ + h * DK_ + lg * 8;
        qf[mf][0][0] = *(const shortx8*)(Qh + off);
        qf[mf][1][0] = *(const shortx8*)(Qh + off + 32);
        qf[mf][0][1] = *(const shortx8*)(Ql + off);
        qf[mf][1][1] = *(const shortx8*)(Ql + off + 32);
    }

    // staging addresses (tile 0)
    const int kr = tid >> 2, kc = (tid & 3) * 16;
    const u16* gKh = Kh + (rowbase + kr) * D_ + h * DK_ + kc;
    const u16* gKl = Kl + (rowbase + kr) * D_ + h * DK_ + kc;
    const u16* gV  = Vh + (rowbase + lane) * D_ + h * DK_ + w * 16;

    shortx8 rkh[2], rkl[2], rv[2];
    rkh[0] = *(const shortx8*)(gKh);     rkh[1] = *(const shortx8*)(gKh + 8);
    rkl[0] = *(const shortx8*)(gKl);     rkl[1] = *(const shortx8*)(gKl + 8);
    rv[0]  = *(const shortx8*)(gV);      rv[1]  = *(const shortx8*)(gV + 8);

    floatx4 zero = {0.f, 0.f, 0.f, 0.f};
    float m_r[2][4], l_r[2][4];
    floatx4 oacc[2][4];
    #pragma unroll
    for (int mf = 0; mf < 2; ++mf) {
        #pragma unroll
        for (int r = 0; r < 4; ++r) { m_r[mf][r] = -1e30f; l_r[mf][r] = 0.f; }
        #pragma unroll
        for (int df = 0; df < 4; ++df) oacc[mf][df] = zero;
    }

    const int nkt = 2 * qt + 2;
    for (int kt = 0; kt < nkt; ++kt) {
        __syncthreads();                       // prev tile's reads done
        *(shortx8*)&Ks[0][kr][kc]     = rkh[0];
        *(shortx8*)&Ks[0][kr][kc + 8] = rkh[1];
        *(shortx8*)&Ks[1][kr][kc]     = rkl[0];
        *(shortx8*)&Ks[1][kr][kc + 8] = rkl[1];
        #pragma unroll
        for (int j = 0; j < 8; ++j) {
            Vt[w * 16 + j][lane]     = (u16)rv[0][j];
            Vt[w * 16 + 8 + j][lane] = (u16)rv[1][j];
        }
        __syncthreads();

        if (kt < nkt - 1) {                    // prefetch next tile into regs
            gKh += (size_t)64 * D_; gKl += (size_t)64 * D_; gV += (size_t)64 * D_;
            rkh[0] = *(const shortx8*)(gKh);   rkh[1] = *(const shortx8*)(gKh + 8);
            rkl[0] = *(const shortx8*)(gKl);   rkl[1] = *(const shortx8*)(gKl + 8);
            rv[0]  = *(const shortx8*)(gV);    rv[1]  = *(const shortx8*)(gV + 8);
        }

        // ---- S = (Q/8) @ K^T  (bf16x3) ----
        floatx4 sc[2][4];
        #pragma unroll
        for (int mf = 0; mf < 2; ++mf)
            #pragma unroll
            for (int nf = 0; nf < 4; ++nf) sc[mf][nf] = zero;
        #pragma unroll
        for (int nf = 0; nf < 4; ++nf)
            #pragma unroll
            for (int ks = 0; ks < 2; ++ks) {
                shortx8 kbh = *(const shortx8*)&Ks[0][nf * 16 + lr][ks * 32 + lg * 8];
                shortx8 kbl = *(const shortx8*)&Ks[1][nf * 16 + lr][ks * 32 + lg * 8];
                #pragma unroll
                for (int mf = 0; mf < 2; ++mf) {
                    sc[mf][nf] = MFMA(qf[mf][ks][0], kbh, sc[mf][nf]);
                    sc[mf][nf] = MFMA(qf[mf][ks][0], kbl, sc[mf][nf]);
                    sc[mf][nf] = MFMA(qf[mf][ks][1], kbh, sc[mf][nf]);
                }
            }

        // ---- causal mask (diagonal zone only) ----
        if (kt >= 2 * qt) {
            #pragma unroll
            for (int mf = 0; mf < 2; ++mf)
                #pragma unroll
                for (int nf = 0; nf < 4; ++nf)
                    #pragma unroll
                    for (int r = 0; r < 4; ++r) {
                        int key = kt * 64 + nf * 16 + lr;
                        int qr  = q0 + w * 32 + mf * 16 + lg * 4 + r;
                        if (key > qr) sc[mf][nf][r] = -1e30f;
                    }
        }

        // ---- online softmax (rows live on 16-lane groups) ----
        float corr[2][4];
        #pragma unroll
        for (int mf = 0; mf < 2; ++mf)
            #pragma unroll
            for (int r = 0; r < 4; ++r) {
                float rm = fmaxf(fmaxf(sc[mf][0][r], sc[mf][1][r]),
                                 fmaxf(sc[mf][2][r], sc[mf][3][r]));
                #pragma unroll
                for (int off = 1; off < 16; off <<= 1)
                    rm = fmaxf(rm, __shfl_xor(rm, off));
                float mn = fmaxf(m_r[mf][r], rm);
                float co = __expf(m_r[mf][r] - mn);
                m_r[mf][r] = mn;
                float rs = 0.f;
                #pragma unroll
                for (int nf = 0; nf < 4; ++nf) {
                    float p = __expf(sc[mf][nf][r] - mn);
                    sc[mf][nf][r] = p;
                    rs += p;
                }
                #pragma unroll
                for (int off = 1; off < 16; off <<= 1)
                    rs += __shfl_xor(rs, off);
                l_r[mf][r] = l_r[mf][r] * co + rs;
                corr[mf][r] = co;
            }
        #pragma unroll
        for (int mf = 0; mf < 2; ++mf)
            #pragma unroll
            for (int df = 0; df < 4; ++df)
                #pragma unroll
                for (int r = 0; r < 4; ++r)
                    oacc[mf][df][r] *= corr[mf][r];

        // ---- P -> LDS (per-wave private; no barrier needed) ----
        #pragma unroll
        for (int mf = 0; mf < 2; ++mf)
            #pragma unroll
            for (int nf = 0; nf < 4; ++nf)
                #pragma unroll
                for (int r = 0; r < 4; ++r)
                    Ps[w][mf * 16 + lg * 4 + r][nf * 16 + lr] = f2bf(sc[mf][nf][r]);

        // ---- O += P @ V ----
        #pragma unroll
        for (int ks = 0; ks < 2; ++ks) {
            shortx8 pa0 = *(const shortx8*)&Ps[w][lr][ks * 32 + lg * 8];
            shortx8 pa1 = *(const shortx8*)&Ps[w][16 + lr][ks * 32 + lg * 8];
            #pragma unroll
            for (int df = 0; df < 4; ++df) {
                shortx8 vb = *(const shortx8*)&Vt[df * 16 + lr][ks * 32 + lg * 8];
                oacc[0][df] = MFMA(pa0, vb, oacc[0][df]);
                oacc[1][df] = MFMA(pa1, vb, oacc[1][df]);
            }
        }
    }

    // ---- epilogue: O /= l, split hi/lo, pair-packed u32 stores ----
    #pragma unroll
    for (int mf = 0; mf < 2; ++mf)
        #pragma unroll
        for (int df = 0; df < 4; ++df)
            #pragma unroll
            for (int r = 0; r < 4; ++r) {
                float o = oacc[mf][df][r] / l_r[mf][r];
                u16 hv = f2bf(o);
                u16 lv = f2bf(o - bf2f(hv));
                u32 ph  = (u32)__shfl_xor((int)hv, 1) & 0xFFFFu;
                u32 pl2 = (u32)__shfl_xor((int)lv, 1) & 0xFFFFu;
                if (!(lr & 1)) {
                    size_t off = (rowbase + q0 + w * 32 + mf * 16 + lg * 4 + r) * D_
                               + h * DK_ + df * 16 + lr;
                    *(u32*)(Oh + off) = (u32)hv | (ph << 16);
                    *(u32*)(Ol + off) = (u32)lv | (pl2 << 16);
                }
            }
}

// ---------------------------------------------------------------------------
// Launch
// ---------------------------------------------------------------------------
extern "C" void kernel_launch(void* const* d_in, const int* in_sizes, int n_in,
                              void* d_out, int out_size, void* d_ws, size_t ws_size,
                              hipStream_t stream)
{
    const float* x   = (const float*)d_in[0];
    const float* w_q = (const float*)d_in[1];
    const float* w_k = (const float*)d_in[2];
    const float* w_v = (const float*)d_in[3];
    const float* w_o = (const float*)d_in[4];
    float* out = (float*)d_out;

    const size_t TEN = (size_t)B_ * S_ * D_;   // 8388608
    const int    DD  = D_ * D_;                // 1048576
    const int    M   = B_ * S_;                // 8192

    u16* p   = (u16*)d_ws;
    u16* xh  = p;            u16* xl  = xh + TEN;
    u16* qh  = xl + TEN;     u16* ql  = qh + TEN;   // -> reused as attn out hi/lo
    u16* kh  = ql + TEN;     u16* kl  = kh + TEN;
    u16* vh  = kl + TEN;
    u16* wp  = vh + TEN;                            // 8 weight planes of DD
    u16* wqh = wp;           u16* wql = wqh + DD;
    u16* wkh = wql + DD;     u16* wkl = wkh + DD;
    u16* wvh = wkl + DD;     u16* wvl = wvh + DD;
    u16* woh = wvl + DD;     u16* wol = woh + DD;

    // 1) split fp32 -> bf16 hi/lo planes
    split_bf16<<<(int)(TEN / 1024), 256, 0, stream>>>(x, xh, xl, (int)TEN);
    split_bf16<<<DD / 1024, 256, 0, stream>>>(w_q, wqh, wql, DD);
    split_bf16<<<DD / 1024, 256, 0, stream>>>(w_k, wkh, wkl, DD);
    split_bf16<<<DD / 1024, 256, 0, stream>>>(w_v, wvh, wvl, DD);
    split_bf16<<<DD / 1024, 256, 0, stream>>>(w_o, woh, wol, DD);

    dim3 gg(M / 128, D_ / 128);                    // (64, 8): x fastest -> W-panel L2 reuse

    // 2) projections (RoPE fused into q,k epilogues; q pre-scaled by 1/8)
    gemm_b3<2><<<gg, 256, 0, stream>>>(xh, xl, wqh, wql, nullptr, qh, ql,
                                       M, D_, D_, 0.125f);
    gemm_b3<2><<<gg, 256, 0, stream>>>(xh, xl, wkh, wkl, nullptr, kh, kl,
                                       M, D_, D_, 1.0f);
    gemm_b3<1><<<gg, 256, 0, stream>>>(xh, xl, wvh, wvl, nullptr, vh, nullptr,
                                       M, D_, D_, 1.0f);

    // 3) flash attention (output aliases q planes; block-disjoint regions)
    attn_mfma<<<dim3(S_ / 128, H_, B_), 256, 0, stream>>>(qh, ql, kh, kl, vh,
                                                          qh, ql);

    // 4) output projection -> fp32
    gemm_b3<0><<<gg, 256, 0, stream>>>(qh, ql, woh, wol, out, nullptr, nullptr,
                                       M, D_, D_, 1.0f);
}